// Round 9
// baseline (1292.608 us; speedup 1.0000x reference)
//
#include <hip/hip_runtime.h>

typedef __attribute__((ext_vector_type(8))) short bf16x8;
typedef __attribute__((ext_vector_type(4))) float f32x4;

__device__ __forceinline__ unsigned short f2bf(float x) {
    unsigned u = __float_as_uint(x);
    u += 0x7FFFu + ((u >> 16) & 1u);
    return (unsigned short)(u >> 16);
}
__device__ __forceinline__ float sigm(float x) { return 1.0f / (1.0f + __expf(-x)); }
__device__ __forceinline__ float ftanh(float x) {
    float e = __expf(2.f * x);
    return 1.f - 2.f / (e + 1.f);
}

// async global->LDS, 16B/lane, wave-uniform LDS base + lane*16
__device__ __forceinline__ void gld16(const unsigned short* g, unsigned short* l) {
    __builtin_amdgcn_global_load_lds((const __attribute__((address_space(1))) void*)g,
                                     (__attribute__((address_space(3))) void*)l, 16, 0, 0);
}

// flag accesses: L2-scope (intra-XCD, fast) and MALL-scope (cross-XCD)
__device__ __forceinline__ unsigned ld_l2(const unsigned* p) {
    unsigned v;
    asm volatile("global_load_dword %0, %1, off sc0\n\ts_waitcnt vmcnt(0)"
                 : "=v"(v) : "v"(p) : "memory");
    return v;
}
__device__ __forceinline__ unsigned ld_mall(const unsigned* p) {
    unsigned v;
    asm volatile("global_load_dword %0, %1, off sc0 sc1\n\ts_waitcnt vmcnt(0)"
                 : "=v"(v) : "v"(p) : "memory");
    return v;
}
__device__ __forceinline__ void st_flag(unsigned* p, unsigned v) {   // write-through: L2 + MALL
    asm volatile("global_store_dword %0, %1, off sc0 sc1" :: "v"(p), "v"(v) : "memory");
}
__device__ __forceinline__ void st_wt16(unsigned short* p, unsigned v) {  // bf16 write-through
    asm volatile("global_store_short %0, %1, off sc0 sc1" :: "v"(p), "v"(v) : "memory");
}

// DPP quad-lane exchanges (replace ds_bpermute shfl_xor: ~120cyc -> 1cyc VALU)
__device__ __forceinline__ float dppx1(float x) {   // lane ^= 1 within quad
    return __int_as_float(__builtin_amdgcn_mov_dpp(__float_as_int(x), 0xB1, 0xF, 0xF, true));
}
__device__ __forceinline__ float dppx2(float x) {   // lane ^= 2 within quad
    return __int_as_float(__builtin_amdgcn_mov_dpp(__float_as_int(x), 0x4E, 0xF, 0xF, true));
}

// ---------------- packing kernels (round-6-verified) ----------------
// Packed activation layout ("frag order"), 512-wide tensors:
//   slot(R,kc,lane): byte = ((R*16+kc)*64+lane)*16; elem e -> k = kc*32+(lane>>4)*8+e
__global__ __launch_bounds__(256) void k_conv_x(const float* __restrict__ x,
                                                unsigned short* __restrict__ Xp) {
    int i = blockIdx.x * 256 + threadIdx.x;
    int rb = i >> 10, kc = (i >> 6) & 15, ln = i & 63;
    int row = (rb << 4) + (ln & 15);
    int k   = (kc << 5) + ((ln >> 4) << 3);
    const float* s = x + (size_t)row * 512 + k;
    float4 v0 = *(const float4*)s, v1 = *(const float4*)(s + 4);
    unsigned short o[8] = {f2bf(v0.x), f2bf(v0.y), f2bf(v0.z), f2bf(v0.w),
                           f2bf(v1.x), f2bf(v1.y), f2bf(v1.z), f2bf(v1.w)};
    *(bf16x8*)(Xp + (size_t)i * 8) = *(bf16x8*)o;
}

__global__ __launch_bounds__(256) void k_conv_w(const float* __restrict__ Wih,
                                                const float* __restrict__ Whh,
                                                unsigned short* __restrict__ Wp) {
    int i = blockIdx.x * 256 + threadIdx.x;
    int wrb = i >> 11, kc = (i >> 6) & 31, ln = i & 63;
    int j = (wrb << 4) + (ln & 15);
    int k = (kc << 5) + ((ln >> 4) << 3);
    int srow = (j & 3) * 512 + (j >> 2);              // torch row g*512+hc
    const float* s = (k < 512) ? (Wih + (size_t)srow * 512 + k)
                               : (Whh + (size_t)srow * 512 + (k - 512));
    float4 v0 = *(const float4*)s, v1 = *(const float4*)(s + 4);
    unsigned short o[8] = {f2bf(v0.x), f2bf(v0.y), f2bf(v0.z), f2bf(v0.w),
                           f2bf(v1.x), f2bf(v1.y), f2bf(v1.z), f2bf(v1.w)};
    *(bf16x8*)(Wp + (size_t)i * 8) = *(bf16x8*)o;
}

struct DP {
    const unsigned short* Xp;
    unsigned short *Hp0, *Hp1, *Hp2;       // recurrence h: PLAIN stores, intra-XCD L2
    unsigned short *Xq1, *Xq2;             // cross-layer x copies: sc1 write-through
    const unsigned short *Wp0, *Wp1, *Wp2;
    const float *bi0, *bh0, *bi1, *bh1, *bi2, *bh2;
    float* Out;
    unsigned int* flags;                   // [0,256) iflag, [256,512) cflag
};

__device__ __forceinline__ void quadT(f32x4 a, int sq, float& G0, float& G1, float& G2, float& G3) {
    float a0 = a[0], a1 = a[1], a2 = a[2], a3 = a[3];
    float p1 = (sq & 1) ? a0 : a1; float g1_ = dppx1(p1);
    float p2 = (sq & 1) ? a2 : a3; float g2_ = dppx1(p2);
    float m0 = (sq & 1) ? g1_ : a0, m1 = (sq & 1) ? a1 : g1_;
    float m2 = (sq & 1) ? g2_ : a2, m3 = (sq & 1) ? a3 : g2_;
    float q1 = (sq & 2) ? m0 : m2; float h1_ = dppx2(q1);
    float q2 = (sq & 2) ? m1 : m3; float h2_ = dppx2(q2);
    G0 = (sq & 2) ? h1_ : m0; G1 = (sq & 2) ? h2_ : m1;
    G2 = (sq & 2) ? m2 : h1_; G3 = (sq & 2) ? m3 : h2_;
}

#define PIN8(A,B,C,D,E,F,G,H) \
    asm volatile("" : "+v"(A),"+v"(B),"+v"(C),"+v"(D),"+v"(E),"+v"(F),"+v"(G),"+v"(H))

// Persistent dilated-LSTM, grid 256, XCD-clustered: cid = bid & 7 -> XCD,
// w = bid >> 3 (32 wgs/cluster co-located on one XCD's 32 CUs).
//   cid 0,1: L0 clusters (rows 0-31 / 32-63), T=256, P=1
//   cid 2,3: L1 clusters (rows 0-63 / 64-127), T=128, P=2
//   cid 4-7: L2 clusters (rows c*64..), T=64, P=2
// Protocol: h recurrence = plain stores into own-XCD L2 (coherent, single
// cache); cross-layer x = sc1 write-through copy into Xq*, gated by MALL
// cflag, published ONE STEP LATE (by then the sc1 stores are provably
// retired: vmcnt in-order + next step's counted wait). Release: plain
// stores, then sc1 stores, s_waitcnt vmcnt(#sc1) waits plain only, RAW
// s_barrier (no vmcnt(0) drain), iflag publish (write-through -> own L2
// for fast sc0 polls + MALL for safety). iflag poll escalates sc0 ->
// sc0sc1 after 2048 idle iters (correct even if bid%8 != XCD).
__global__ __launch_bounds__(256, 1) void k_drnn(DP p) {
    const int tid = threadIdx.x, lane = tid & 63, wv = tid >> 6;
    const int l15 = lane & 15, lhi = lane >> 4, sq = l15 & 3;

    const int b = blockIdx.x;
    const int cid = b & 7, w = b >> 3;
    int l, c, T, P, N;
    if (cid < 2)      { l = 0; c = cid;     T = 256; P = 1; N = 64;  }
    else if (cid < 4) { l = 1; c = cid - 2; T = 128; P = 2; N = 128; }
    else              { l = 2; c = cid - 4; T = 64;  P = 2; N = 256; }

    const unsigned short* Xs = (l == 0) ? p.Xp  : (l == 1 ? p.Xq1 : p.Xq2);
    unsigned short*       Hd = (l == 0) ? p.Hp0 : (l == 1 ? p.Hp1 : p.Hp2);
    unsigned short*       Xw = (l == 0) ? p.Xq1 : (l == 1 ? p.Xq2 : nullptr);
    const unsigned short* Ws = (l == 0) ? p.Wp0 : (l == 1 ? p.Wp1 : p.Wp2);
    const float* bi = (l == 0) ? p.bi0 : (l == 1 ? p.bi1 : p.bi2);
    const float* bh = (l == 0) ? p.bh0 : (l == 1 ? p.bh1 : p.bh2);
    const int R0 = c * (P * 32);

    __shared__ unsigned short At[65536];   // 128 KiB

    // ---- W: 64 packed rows in 32 named bf16x8 regs (lands in AGPRs, r7-verified)
    const unsigned short* wbase = Ws + ((size_t)(((w << 2) + wv) * 32) << 9) + lane * 8;
#define DECLW(n) bf16x8 w##n = *(const bf16x8*)(wbase + (n << 9));
    DECLW(0) DECLW(1) DECLW(2) DECLW(3) DECLW(4) DECLW(5) DECLW(6) DECLW(7)
    DECLW(8) DECLW(9) DECLW(10) DECLW(11) DECLW(12) DECLW(13) DECLW(14) DECLW(15)
    DECLW(16) DECLW(17) DECLW(18) DECLW(19) DECLW(20) DECLW(21) DECLW(22) DECLW(23)
    DECLW(24) DECLW(25) DECLW(26) DECLW(27) DECLW(28) DECLW(29) DECLW(30) DECLW(31)

    const int hcol = (w << 4) + (wv << 2) + (l15 >> 2);
    const float bs0 = bi[hcol]        + bh[hcol];
    const float bs1 = bi[512 + hcol]  + bh[512 + hcol];
    const float bs2 = bi[1024 + hcol] + bh[1024 + hcol];
    const float bs3 = bi[1536 + hcol] + bh[1536 + hcol];

    const int kch = hcol >> 5;
    const int lane16 = (((hcol & 31) >> 3) << 4) + ((lhi << 2) + sq);
    const int st_lt = lane16 * 8 + (hcol & 7);

    float cst0 = 0.f, cst1 = 0.f, cst2 = 0.f, cst3 = 0.f;
    unsigned int* iflag = p.flags;
    unsigned int* cflag = p.flags + 256;
    int fastok = 1;

#define KPn(na, nb) { \
    bf16x8 xa = *(const bf16x8*)(a0 + ((na) << 9)); \
    bf16x8 xb = *(const bf16x8*)(a1 + ((na) << 9)); \
    bf16x8 ya = *(const bf16x8*)(a0 + ((nb) << 9)); \
    bf16x8 yb = *(const bf16x8*)(a1 + ((nb) << 9)); \
    e0 = __builtin_amdgcn_mfma_f32_16x16x32_bf16(xa, w##na, e0, 0, 0, 0); \
    e1 = __builtin_amdgcn_mfma_f32_16x16x32_bf16(xb, w##na, e1, 0, 0, 0); \
    o0 = __builtin_amdgcn_mfma_f32_16x16x32_bf16(ya, w##nb, o0, 0, 0, 0); \
    o1 = __builtin_amdgcn_mfma_f32_16x16x32_bf16(yb, w##nb, o1, 0, 0, 0); }

#define PWC(RV, CSTV, HV) { \
    float G0, G1, G2, G3; quadT(RV, sq, G0, G1, G2, G3); \
    float cn = sigm(G1 + bs1) * CSTV + sigm(G0 + bs0) * ftanh(G2 + bs2); \
    HV = sigm(G3 + bs3) * ftanh(cn); CSTV = cn; }

#define DOPASS(PI, CA, CB, HA, HB) { \
    const unsigned short* a0 = At + (((PI) * 64) << 9) + lane * 8; \
    const unsigned short* a1 = a0 + (32 << 9); \
    f32x4 e0 = {0.f,0.f,0.f,0.f}, o0 = {0.f,0.f,0.f,0.f}; \
    f32x4 e1 = {0.f,0.f,0.f,0.f}, o1 = {0.f,0.f,0.f,0.f}; \
    KPn(0,1) KPn(2,3) KPn(4,5) KPn(6,7) KPn(8,9) KPn(10,11) KPn(12,13) KPn(14,15) \
    KPn(16,17) KPn(18,19) KPn(20,21) KPn(22,23) KPn(24,25) KPn(26,27) KPn(28,29) KPn(30,31) \
    f32x4 r0 = e0 + o0, r1 = e1 + o1; \
    PWC(r0, CA, HA) PWC(r1, CB, HB) }

    for (int t = 0; t < T; ++t) {
        PIN8(w0,w1,w2,w3,w4,w5,w6,w7);
        PIN8(w8,w9,w10,w11,w12,w13,w14,w15);
        PIN8(w16,w17,w18,w19,w20,w21,w22,w23);
        PIN8(w24,w25,w26,w27,w28,w29,w30,w31);

        const int RxB = (t * N + R0) >> 4;

        if (l == 0) {   // prefetch x (static input) before the dependency wait
            #pragma unroll
            for (int i = 0; i < 8; ++i) {
                int q = (wv << 3) + i, rb = q >> 4, kc = q & 15;
                gld16(Xs + ((size_t)((RxB + rb) * 16 + kc) << 9) + lane * 8,
                      &At[(rb * 32 + kc) << 9]);
            }
        }

        // ---- waits: wave0 = own cluster (L2-scope, adaptive); wave1 = producer (MALL)
        if (wv == 0 && t > 0) {
            const unsigned* fp = iflag + cid * 32 + (lane & 31);
            const unsigned need = (unsigned)t;
            int n = 0;
            for (;;) {
                unsigned v = fastok ? ld_l2(fp) : ld_mall(fp);
                if (__all((lane >= 32) || (v >= need))) break;
                if (fastok && ++n > 2048) fastok = 0;   // escalate if XCD-local never lands
            }
        }
        if (wv == 1 && l == 1) {
            const unsigned* fp = cflag + lane;           // L0 c0: lanes 0-31, c1: 32-63
            const unsigned need = (unsigned)(2 * t + (lane >> 5) + 1);
            int n = 0;
            for (;;) {
                unsigned v = ld_mall(fp);
                if (__all(v >= need)) break;
                if (++n > (1 << 22)) break;
            }
        }
        if (wv == 1 && l == 2) {
            const unsigned* fp = cflag + (2 + (c & 1)) * 32 + (lane & 31);
            const unsigned need = (unsigned)(2 * t + (c >> 1) + 1);
            int n = 0;
            for (;;) {
                unsigned v = ld_mall(fp);
                if (__all((lane >= 32) || (v >= need))) break;
                if (++n > (1 << 22)) break;
            }
        }
        __syncthreads();                              // B0

        float hv0, hv1, hv2 = 0.f, hv3 = 0.f;
        if (l == 0) {
            if (t > 0) {
                const int RhB = ((t - 1) * N + R0) >> 4;
                #pragma unroll
                for (int i = 0; i < 8; ++i) {
                    int q = (wv << 3) + i, rb = q >> 4, kc = q & 15;
                    gld16(Hd + ((size_t)((RhB + rb) * 16 + kc) << 9) + lane * 8,
                          &At[(rb * 32 + 16 + kc) << 9]);
                }
            } else {
                #pragma unroll
                for (int rb = 0; rb < 2; ++rb)
                    #pragma unroll
                    for (int it = 0; it < 4; ++it)
                        *(float4*)&At[((rb * 32 + 16) << 9) + (it * 256 + tid) * 8] =
                            (float4){0.f, 0.f, 0.f, 0.f};
            }
            __builtin_amdgcn_sched_barrier(0);

            const unsigned short* a0 = At + lane * 8;
            const unsigned short* a1 = a0 + (32 << 9);
            f32x4 e0 = {0.f,0.f,0.f,0.f}, o0 = {0.f,0.f,0.f,0.f};
            f32x4 e1 = {0.f,0.f,0.f,0.f}, o1 = {0.f,0.f,0.f,0.f};
            KPn(0,1) KPn(2,3) KPn(4,5) KPn(6,7)
            KPn(8,9) KPn(10,11) KPn(12,13) KPn(14,15)
            __syncthreads();                          // B1 (h staged)
            KPn(16,17) KPn(18,19) KPn(20,21) KPn(22,23)
            KPn(24,25) KPn(26,27) KPn(28,29) KPn(30,31)
            f32x4 r0 = e0 + o0, r1 = e1 + o1;
            PWC(r0, cst0, hv0) PWC(r1, cst1, hv1)
        } else {
            #pragma unroll
            for (int i = 0; i < 16; ++i) {
                int q = (wv << 4) + i, rb = q >> 4, kc = q & 15;
                gld16(Xs + ((size_t)((RxB + rb) * 16 + kc) << 9) + lane * 8,
                      &At[(rb * 32 + kc) << 9]);
            }
            if (t > 0) {
                const int RhB = ((t - 1) * N + R0) >> 4;
                #pragma unroll
                for (int i = 0; i < 16; ++i) {
                    int q = (wv << 4) + i, rb = q >> 4, kc = q & 15;
                    gld16(Hd + ((size_t)((RhB + rb) * 16 + kc) << 9) + lane * 8,
                          &At[(rb * 32 + 16 + kc) << 9]);
                }
            } else {
                #pragma unroll
                for (int rb = 0; rb < 4; ++rb)
                    #pragma unroll
                    for (int it = 0; it < 4; ++it)
                        *(float4*)&At[((rb * 32 + 16) << 9) + (it * 256 + tid) * 8] =
                            (float4){0.f, 0.f, 0.f, 0.f};
            }
            __syncthreads();                          // B1
            DOPASS(0, cst0, cst1, hv0, hv1)
            DOPASS(1, cst2, cst3, hv2, hv3)
        }

        // ---- release: plain stores first, sc1 copies second, wait plain only
        const unsigned short hb0 = f2bf(hv0), hb1 = f2bf(hv1);
        const unsigned short hb2 = f2bf(hv2), hb3 = f2bf(hv3);
        const size_t i0 = ((size_t)((RxB + 0) * 16 + kch) << 9) + st_lt;
        const size_t i1 = ((size_t)((RxB + 1) * 16 + kch) << 9) + st_lt;
        const size_t i2 = ((size_t)((RxB + 2) * 16 + kch) << 9) + st_lt;
        const size_t i3 = ((size_t)((RxB + 3) * 16 + kch) << 9) + st_lt;
        Hd[i0] = hb0; Hd[i1] = hb1;
        if (P == 2) { Hd[i2] = hb2; Hd[i3] = hb3; }
        if (l == 2) {
            p.Out[((size_t)(((RxB + 0) << 4) + (lhi << 2) + sq)) * 512 + hcol] = hv0;
            p.Out[((size_t)(((RxB + 1) << 4) + (lhi << 2) + sq)) * 512 + hcol] = hv1;
            p.Out[((size_t)(((RxB + 2) << 4) + (lhi << 2) + sq)) * 512 + hcol] = hv2;
            p.Out[((size_t)(((RxB + 3) << 4) + (lhi << 2) + sq)) * 512 + hcol] = hv3;
        }
        asm volatile("" ::: "memory");
        __builtin_amdgcn_sched_barrier(0);
        if (l == 0) { st_wt16(Xw + i0, hb0); st_wt16(Xw + i1, hb1); }
        else if (l == 1) { st_wt16(Xw + i0, hb0); st_wt16(Xw + i1, hb1);
                           st_wt16(Xw + i2, hb2); st_wt16(Xw + i3, hb3); }
        __builtin_amdgcn_sched_barrier(0);
        if (l == 0)      asm volatile("s_waitcnt vmcnt(2)" ::: "memory");  // plain done
        else if (l == 1) asm volatile("s_waitcnt vmcnt(4)" ::: "memory");
        else             asm volatile("s_waitcnt vmcnt(0)" ::: "memory");  // all plain
        __builtin_amdgcn_sched_barrier(0);
        __builtin_amdgcn_s_barrier();                 // B2 (raw: no vmcnt(0) drain)
        __builtin_amdgcn_sched_barrier(0);
        if (tid == 0) {
            st_flag(iflag + cid * 32 + w, (unsigned)(t + 1));          // own cluster
            if (l < 2 && t > 0) st_flag(cflag + cid * 32 + w, (unsigned)t);  // delayed: step t-1 MALL-safe
        }
    }

    // drain everything, then publish final cross-layer flag
    asm volatile("s_waitcnt vmcnt(0)" ::: "memory");
    __builtin_amdgcn_s_barrier();
    if (tid == 0 && l < 2) st_flag(cflag + cid * 32 + w, (unsigned)T);
}

extern "C" void kernel_launch(void* const* d_in, const int* in_sizes, int n_in,
                              void* d_out, int out_size, void* d_ws, size_t ws_size,
                              hipStream_t stream)
{
    const float* x = (const float*)d_in[0];
    const float* Wih[3] = {(const float*)d_in[1], (const float*)d_in[5], (const float*)d_in[9]};
    const float* Whh[3] = {(const float*)d_in[2], (const float*)d_in[6], (const float*)d_in[10]};
    const float* bih[3] = {(const float*)d_in[3], (const float*)d_in[7], (const float*)d_in[11]};
    const float* bhh[3] = {(const float*)d_in[4], (const float*)d_in[8], (const float*)d_in[12]};

    char* wp = (char*)d_ws;
    const size_t SZ_A = (size_t)16384 * 512;
    unsigned int* flags = (unsigned int*)wp; wp += 4096;
    unsigned short* Xp  = (unsigned short*)wp; wp += SZ_A * 2;
    unsigned short* Hp0 = (unsigned short*)wp; wp += SZ_A * 2;
    unsigned short* Hp1 = (unsigned short*)wp; wp += SZ_A * 2;
    unsigned short* Hp2 = (unsigned short*)wp; wp += SZ_A * 2;
    unsigned short* Wp[3];
    for (int l = 0; l < 3; ++l) { Wp[l] = (unsigned short*)wp; wp += (size_t)2048 * 1024 * 2; }
    unsigned short* Xq1 = (unsigned short*)wp; wp += SZ_A * 2;
    unsigned short* Xq2 = (unsigned short*)wp; wp += SZ_A * 2;
    // fallback if ws too small: alias the cross-layer copies onto the h buffers
    // (dual store then writes identical bytes twice -> benign, = round-7 path)
    const size_t need = (size_t)(wp - (char*)d_ws);
    if (ws_size < need) { Xq1 = Hp0; Xq2 = Hp1; }

    hipMemsetAsync(flags, 0, 4096, stream);
    k_conv_x<<<dim3(4096), dim3(256), 0, stream>>>(x, Xp);
    for (int l = 0; l < 3; ++l)
        k_conv_w<<<dim3(1024), dim3(256), 0, stream>>>(Wih[l], Whh[l], Wp[l]);

    DP dp;
    dp.Xp = Xp; dp.Hp0 = Hp0; dp.Hp1 = Hp1; dp.Hp2 = Hp2;
    dp.Xq1 = Xq1; dp.Xq2 = Xq2;
    dp.Wp0 = Wp[0]; dp.Wp1 = Wp[1]; dp.Wp2 = Wp[2];
    dp.bi0 = bih[0]; dp.bh0 = bhh[0];
    dp.bi1 = bih[1]; dp.bh1 = bhh[1];
    dp.bi2 = bih[2]; dp.bh2 = bhh[2];
    dp.Out = (float*)d_out; dp.flags = flags;

    k_drnn<<<dim3(256), dim3(256), 0, stream>>>(dp);
}